// Round 1
// baseline (199.416 us; speedup 1.0000x reference)
//
#include <hip/hip_runtime.h>

#define T_LEN   65536
#define BATCH   256
#define P       64
#define K1_LEN  8192
#define DBLK    256

// ---------------------------------------------------------------------------
// means[t] = bias * R[t] where R is the STEP RESPONSE of the AR(64) filter:
//   R[t] = sum_k params[k]*R[t-1-k] + 1,  R[t<0] = 0
// Extension identity (companion-matrix first-row = short conv of impulse
// response with params):
//   R[L+tau] = R[tau] + sum_{i=0}^{64} V[i]*R[tau-i]
//   V[i] = W[i]-W[i-1],  W[j] = sum_{m=0}^{63-j} params[m+j]*R[L-1-m]
// ---------------------------------------------------------------------------

// Phase 1a: serial 64 steps (transposed-form IIR on wave 0) + in-LDS doubling
// 64 -> 8192, single workgroup.
__global__ __launch_bounds__(1024) void ar_k1(const float* __restrict__ params,
                                              float* __restrict__ R) {
    __shared__ float Rl[K1_LEN];
    __shared__ float p[P];
    __shared__ float V[P + 1];
    const int tid = threadIdx.x;
    if (tid < P) p[tid] = params[tid];
    __syncthreads();

    // Serial stage: lane k holds transposed-form state z_{k+1}.
    // y = z1 + 1; z_k' = params[k-1]*y + z_{k+1}; z_64' = params[63]*y.
    if (tid < 64) {
        float z = 0.f;
        const float pk = p[tid];
        for (int t = 0; t < 64; ++t) {
            float y  = __shfl(z, 0) + 1.0f;   // R[t]
            float zn = __shfl_down(z, 1);
            if (tid == 63) zn = 0.f;
            z = fmaf(pk, y, zn);
            if (tid == 0) Rl[t] = y;
        }
    }
    __syncthreads();

    for (int L = 64; L < K1_LEN; L <<= 1) {
        if (tid <= P) {
            const int j = tid;
            float W0 = 0.f, W1 = 0.f;
            if (j <= P - 1)
                for (int m = 0; m <= P - 1 - j; ++m) W0 = fmaf(p[m + j], Rl[L - 1 - m], W0);
            if (j >= 1)
                for (int m = 0; m <= P - j; ++m) W1 = fmaf(p[m + j - 1], Rl[L - 1 - m], W1);
            V[j] = W0 - W1;
        }
        __syncthreads();
        // boundary outputs tau in [0,64): R[tau-i]=0 for i>tau
        if (tid < 64) {
            const int tau = tid;
            float acc = Rl[tau];
            for (int i = 0; i <= tau; ++i) acc = fmaf(V[i], Rl[tau - i], acc);
            Rl[L + tau] = acc;
        }
        // blocked outputs tau in [64,L): 4 per item, register sliding window
        // (cuts per-output LDS reads 65 -> 17, K1 is LDS-BW bound on one CU)
        const int nq = (L - 64) >> 2;
        for (int q = tid; q < nq; q += 1024) {
            const int base = q << 2;          // = tau0 - 64
            float w[68];
            #pragma unroll
            for (int j = 0; j < 68; ++j) w[j] = Rl[base + j];
            float a0 = w[64], a1 = w[65], a2 = w[66], a3 = w[67];
            #pragma unroll
            for (int i = 0; i <= P; ++i) {
                const float vi = V[i];
                a0 = fmaf(vi, w[64 - i], a0);
                a1 = fmaf(vi, w[65 - i], a1);
                a2 = fmaf(vi, w[66 - i], a2);
                a3 = fmaf(vi, w[67 - i], a3);
            }
            const int t0 = L + 64 + base;
            Rl[t0]     = a0;
            Rl[t0 + 1] = a1;
            Rl[t0 + 2] = a2;
            Rl[t0 + 3] = a3;
        }
        __syncthreads();
    }

    for (int j = tid; j < K1_LEN / 4; j += 1024)
        reinterpret_cast<float4*>(R)[j] = reinterpret_cast<const float4*>(Rl)[j];
}

// Phase 1b: grid-wide doubling R[0..L) -> R[L..2L). Each block redundantly
// computes the 65 taps (tiny) then FIRs its 256-output window from LDS.
__global__ __launch_bounds__(DBLK) void ar_double(const float* __restrict__ params,
                                                  float* __restrict__ R, const int L) {
    __shared__ float p[P];
    __shared__ float V[P + 1];
    __shared__ float win[DBLK + P];
    const int tid = threadIdx.x;
    const int B0  = blockIdx.x * DBLK;
    if (tid < P) p[tid] = params[tid];
    __syncthreads();
    if (tid <= P) {
        const int j = tid;
        float W0 = 0.f, W1 = 0.f;
        if (j <= P - 1)
            for (int m = 0; m <= P - 1 - j; ++m) W0 = fmaf(p[m + j], R[L - 1 - m], W0);
        if (j >= 1)
            for (int m = 0; m <= P - j; ++m) W1 = fmaf(p[m + j - 1], R[L - 1 - m], W1);
        V[j] = W0 - W1;
    }
    for (int j = tid; j < DBLK + P; j += DBLK) {
        const int g = B0 - P + j;
        win[j] = (g >= 0) ? R[g] : 0.f;   // zero-pad only affects block 0
    }
    __syncthreads();
    float acc = win[P + tid];
    #pragma unroll
    for (int i = 0; i <= P; ++i) acc = fmaf(V[i], win[P + tid - i], acc);
    R[L + B0 + tid] = acc;
}

// Phase 2: out[b,t] = bias*R[t] + 0.3*noise[b,t]  (memory-bound, float4)
__global__ __launch_bounds__(256) void ar_out(const float* __restrict__ R,
                                              const float* __restrict__ bias,
                                              const float* __restrict__ noise,
                                              float* __restrict__ out) {
    const int i4 = blockIdx.x * 256 + threadIdx.x;       // float4 index
    const float b = bias[0];
    const int t4 = i4 & (T_LEN / 4 - 1);                 // T divisible by 4
    const float4 r4 = reinterpret_cast<const float4*>(R)[t4];
    const float4 n4 = reinterpret_cast<const float4*>(noise)[i4];
    float4 o;
    o.x = fmaf(0.3f, n4.x, b * r4.x);
    o.y = fmaf(0.3f, n4.y, b * r4.y);
    o.z = fmaf(0.3f, n4.z, b * r4.z);
    o.w = fmaf(0.3f, n4.w, b * r4.w);
    reinterpret_cast<float4*>(out)[i4] = o;
}

extern "C" void kernel_launch(void* const* d_in, const int* in_sizes, int n_in,
                              void* d_out, int out_size, void* d_ws, size_t ws_size,
                              hipStream_t stream) {
    const float* params = (const float*)d_in[0];
    const float* bias   = (const float*)d_in[1];
    const float* noise  = (const float*)d_in[2];
    float* out = (float*)d_out;
    float* R   = (float*)d_ws;              // 65536 floats = 256 KiB scratch

    hipLaunchKernelGGL(ar_k1, dim3(1), dim3(1024), 0, stream, params, R);
    for (int L = K1_LEN; L < T_LEN; L <<= 1)
        hipLaunchKernelGGL(ar_double, dim3(L / DBLK), dim3(DBLK), 0, stream,
                           params, R, L);
    hipLaunchKernelGGL(ar_out, dim3((BATCH * (T_LEN / 4)) / 256), dim3(256),
                       0, stream, R, bias, noise, out);
}